// Round 2
// baseline (20364.297 us; speedup 1.0000x reference)
//
#include <hip/hip_runtime.h>
#include <math.h>

#define T_STEPS 16384
#define IN_DIM  14
#define H_DIM   100
#define G_DIM   300   // 3*H

// ---------------- Phase 0: gi0[t][j] = b_ih0[j] + sum_k x[t][k]*w_ih0[j][k] ----------------
__global__ void gi0_kernel(const float* __restrict__ x,
                           const float* __restrict__ w_ih0,
                           const float* __restrict__ b_ih0,
                           float* __restrict__ gi0) {
    int e = blockIdx.x * blockDim.x + threadIdx.x;
    if (e >= T_STEPS * G_DIM) return;
    int t = e / G_DIM;
    int j = e - t * G_DIM;
    const float* xr = x + t * IN_DIM;
    const float* wr = w_ih0 + j * IN_DIM;
    float acc = b_ih0[j];
    #pragma unroll
    for (int k = 0; k < IN_DIM; ++k) acc = fmaf(xr[k], wr[k], acc);
    gi0[e] = acc;
}

// ---------------- Phase 1: persistent single-workgroup sequential GRU ----------------
__device__ __forceinline__ float sig_(float x) { return 1.0f / (1.0f + expf(-x)); }

// 512 threads = 8 waves = 2 waves/SIMD -> 256-VGPR cap. Threads 0..449 each own
// TWO 100-float weight rows (200 VGPRs) so the whole 360 KB weight state lives
// in the CU's 512 KB register file. 960-thread/128-cap variant spilled (VGPR=64,
// FETCH 10 GB) -- do not regress this.
__global__ __launch_bounds__(512, 2)
void gru_seq_kernel(const float* __restrict__ gi0,
                    const float* __restrict__ w_hh0,
                    const float* __restrict__ b_hh0,
                    const float* __restrict__ w_ih1,
                    const float* __restrict__ b_ih1,
                    const float* __restrict__ w_hh1,
                    const float* __restrict__ b_hh1,
                    const float* __restrict__ fc_w,
                    const float* __restrict__ fc_b,
                    float* __restrict__ out) {
    // h1 at hbuf[0..100), h2 at hbuf[128..228)
    __shared__ __align__(16) float hbuf[256];
    __shared__ __align__(16) float gh[3 * G_DIM]; // [0,300) l0-rec, [300,600) l1-in, [600,900) l1-rec

    const int tid = threadIdx.x;
    const int idx = (tid < 450) ? tid : 449;      // tail threads duplicate 449, never write
    const int g   = idx / 150;                    // 0: w_hh0 (vs h1), 1: w_ih1 (vs h1), 2: w_hh1 (vs h2)
    const int pr  = idx - g * 150;
    const int r0  = 2 * pr;
    const bool active = (tid < 450);

    const float* wbase; const float* bbase;
    if (g == 0)      { wbase = w_hh0; bbase = b_hh0; }
    else if (g == 1) { wbase = w_ih1; bbase = b_ih1; }
    else             { wbase = w_hh1; bbase = b_hh1; }
    const float bias0 = bbase[r0];
    const float bias1 = bbase[r0 + 1];
    const int hoff4 = (g == 2) ? 32 : 0;          // float4 index of h2 vs h1
    const int ghw   = (g * G_DIM) / 2 + pr;       // float2 index for gate-preact store

    // Load the two weight rows into registers (2 x 100 floats)
    float w0[H_DIM], w1[H_DIM];
    {
        const float4* p0 = reinterpret_cast<const float4*>(wbase + (size_t)r0 * H_DIM);
        const float4* p1 = reinterpret_cast<const float4*>(wbase + (size_t)(r0 + 1) * H_DIM);
        #pragma unroll
        for (int k = 0; k < H_DIM / 4; ++k) {
            float4 a = p0[k];
            w0[4*k+0] = a.x; w0[4*k+1] = a.y; w0[4*k+2] = a.z; w0[4*k+3] = a.w;
            float4 b = p1[k];
            w1[4*k+0] = b.x; w1[4*k+1] = b.y; w1[4*k+2] = b.z; w1[4*k+3] = b.w;
        }
    }

    if (tid < 256) hbuf[tid] = 0.0f;
    __syncthreads();

    const float4* hb4 = reinterpret_cast<const float4*>(hbuf);
    float2* gh2 = reinterpret_cast<float2*>(gh);

    for (int i = 0; i <= T_STEPS; ++i) {
        // Prefetch gi0 row i (layer-0 gate threads); dot phase covers the latency
        float gr = 0.f, gz = 0.f, gn = 0.f;
        if (tid < H_DIM && i < T_STEPS) {
            const float* p = gi0 + (size_t)i * G_DIM + tid;
            gr = p[0]; gz = p[H_DIM]; gn = p[2 * H_DIM];
        }

        // Dot phase: each thread computes 2 gate pre-activations (shared h loads)
        float a0 = bias0, a1 = 0.0f, b0 = bias1, b1 = 0.0f;
        #pragma unroll
        for (int k = 0; k < H_DIM / 4; ++k) {
            float4 v = hb4[hoff4 + k];
            a0 = fmaf(w0[4*k+0], v.x, a0);
            a1 = fmaf(w0[4*k+1], v.y, a1);
            a0 = fmaf(w0[4*k+2], v.z, a0);
            a1 = fmaf(w0[4*k+3], v.w, a1);
            b0 = fmaf(w1[4*k+0], v.x, b0);
            b1 = fmaf(w1[4*k+1], v.y, b1);
            b0 = fmaf(w1[4*k+2], v.z, b0);
            b1 = fmaf(w1[4*k+3], v.w, b1);
        }
        if (active) gh2[ghw] = make_float2(a0 + a1, b0 + b1);
        __syncthreads();

        // Gate phase
        if (tid < H_DIM) {
            if (i < T_STEPS) {   // h1[i]
                float r = sig_(gr + gh[tid]);
                float z = sig_(gz + gh[H_DIM + tid]);
                float n = tanhf(gn + r * gh[2 * H_DIM + tid]);
                float hp = hbuf[tid];
                hbuf[tid] = (1.0f - z) * n + z * hp;
            }
        } else if (tid >= 256 && tid < 256 + H_DIM) {
            if (i >= 1) {        // h2[i-1]
                int j = tid - 256;
                float r = sig_(gh[G_DIM + j] + gh[2 * G_DIM + j]);
                float z = sig_(gh[G_DIM + H_DIM + j] + gh[2 * G_DIM + H_DIM + j]);
                float n = tanhf(gh[G_DIM + 2 * H_DIM + j] + r * gh[2 * G_DIM + 2 * H_DIM + j]);
                float hp = hbuf[128 + j];
                hbuf[128 + j] = (1.0f - z) * n + z * hp;
            }
        }
        __syncthreads();
    }

    // FC epilogue: out = fc_b + fc_w . h2[T-1]
    if (tid < 64) {
        float s = 0.0f;
        for (int j = tid; j < H_DIM; j += 64) s = fmaf(fc_w[j], hbuf[128 + j], s);
        #pragma unroll
        for (int off = 32; off > 0; off >>= 1) s += __shfl_down(s, off);
        if (tid == 0) out[0] = s + fc_b[0];
    }
}

extern "C" void kernel_launch(void* const* d_in, const int* in_sizes, int n_in,
                              void* d_out, int out_size, void* d_ws, size_t ws_size,
                              hipStream_t stream) {
    const float* x     = (const float*)d_in[0];
    const float* w_ih0 = (const float*)d_in[1];
    const float* w_hh0 = (const float*)d_in[2];
    const float* b_ih0 = (const float*)d_in[3];
    const float* b_hh0 = (const float*)d_in[4];
    const float* w_ih1 = (const float*)d_in[5];
    const float* w_hh1 = (const float*)d_in[6];
    const float* b_ih1 = (const float*)d_in[7];
    const float* b_hh1 = (const float*)d_in[8];
    const float* fc_w  = (const float*)d_in[9];
    const float* fc_b  = (const float*)d_in[10];
    float* out = (float*)d_out;
    float* gi0 = (float*)d_ws;   // T*300 floats = 19.66 MB

    const int total = T_STEPS * G_DIM;
    gi0_kernel<<<(total + 255) / 256, 256, 0, stream>>>(x, w_ih0, b_ih0, gi0);
    gru_seq_kernel<<<1, 512, 0, stream>>>(gi0, w_hh0, b_hh0, w_ih1, b_ih1,
                                          w_hh1, b_hh1, fc_w, fc_b, out);
}

// Round 3
// 15657.217 us; speedup vs baseline: 1.3006x; 1.3006x over previous
//
#include <hip/hip_runtime.h>
#include <math.h>

#define T_STEPS 16384
#define IN_DIM  14
#define H_DIM   100
#define G_DIM   300   // 3*H

typedef float f2 __attribute__((ext_vector_type(2)));

#define REP25(M) M(0) M(1) M(2) M(3) M(4) M(5) M(6) M(7) M(8) M(9) M(10) M(11) \
                 M(12) M(13) M(14) M(15) M(16) M(17) M(18) M(19) M(20) M(21) M(22) M(23) M(24)

// ---------------- Phase 0: gi0[t][j] = b_ih0[j] + sum_k x[t][k]*w_ih0[j][k] ----------------
__global__ void gi0_kernel(const float* __restrict__ x,
                           const float* __restrict__ w_ih0,
                           const float* __restrict__ b_ih0,
                           float* __restrict__ gi0) {
    int e = blockIdx.x * blockDim.x + threadIdx.x;
    if (e >= T_STEPS * G_DIM) return;
    int t = e / G_DIM;
    int j = e - t * G_DIM;
    const float* xr = x + t * IN_DIM;
    const float* wr = w_ih0 + j * IN_DIM;
    float acc = b_ih0[j];
    #pragma unroll
    for (int k = 0; k < IN_DIM; ++k) acc = fmaf(xr[k], wr[k], acc);
    gi0[e] = acc;
}

// ---------------- Phase 1: persistent single-workgroup sequential GRU ----------------
// 512 threads = 8 waves = 2 waves/SIMD -> 256-VGPR cap. Threads 0..449 own TWO
// 100-float weight rows held as 100 NAMED float2 SSA values (macro-generated,
// literal indices) -- float arrays w[100] go to scratch because SROA runs before
// loop unrolling (rounds 1-2: VGPR=64/128, FETCH 10 GB re-streaming). Do not
// convert these back to arrays. float2 arithmetic -> v_pk_fma_f32 (half the
// VALU instrs of scalar fmaf).
__global__ __launch_bounds__(512, 2)
void gru_seq_kernel(const float* __restrict__ gi0,
                    const float* __restrict__ w_hh0,
                    const float* __restrict__ b_hh0,
                    const float* __restrict__ w_ih1,
                    const float* __restrict__ b_ih1,
                    const float* __restrict__ w_hh1,
                    const float* __restrict__ b_hh1,
                    const float* __restrict__ fc_w,
                    const float* __restrict__ fc_b,
                    float* __restrict__ out) {
    // h1 at hbuf[0..100), h2 at hbuf[128..228)
    __shared__ __align__(16) float hbuf[256];
    __shared__ __align__(16) float gh[3 * G_DIM]; // [0,300) l0-rec, [300,600) l1-in, [600,900) l1-rec

    const int tid = threadIdx.x;
    const int idx = (tid < 450) ? tid : 449;      // tail threads duplicate row 449, never write
    const int g   = idx / 150;                    // 0: w_hh0 (vs h1), 1: w_ih1 (vs h1), 2: w_hh1 (vs h2)
    const int pr  = idx - g * 150;
    const int r0  = 2 * pr;
    const bool active = (tid < 450);

    const float* wbase; const float* bbase;
    if (g == 0)      { wbase = w_hh0; bbase = b_hh0; }
    else if (g == 1) { wbase = w_ih1; bbase = b_ih1; }
    else             { wbase = w_hh1; bbase = b_hh1; }
    const float bias0 = bbase[r0];
    const float bias1 = bbase[r0 + 1];
    const int hoff4 = (g == 2) ? 32 : 0;          // float4 index of h2 vs h1
    const int ghw   = (g * G_DIM) / 2 + pr;       // float2 index for gate-preact store

    // ---- weight registers: 100 named f2 values (200 VGPRs), guaranteed SSA ----
    #define DECLK(k) f2 w0a_##k, w0b_##k, w1a_##k, w1b_##k;
    REP25(DECLK)
    #undef DECLK
    {
        const float4* p0 = reinterpret_cast<const float4*>(wbase + (size_t)r0 * H_DIM);
        const float4* p1 = reinterpret_cast<const float4*>(wbase + (size_t)(r0 + 1) * H_DIM);
        #define LOADK(k) { float4 A = p0[k]; w0a_##k.x = A.x; w0a_##k.y = A.y; w0b_##k.x = A.z; w0b_##k.y = A.w; \
                           float4 B = p1[k]; w1a_##k.x = B.x; w1a_##k.y = B.y; w1b_##k.x = B.z; w1b_##k.y = B.w; }
        REP25(LOADK)
        #undef LOADK
    }

    if (tid < 256) hbuf[tid] = 0.0f;
    __syncthreads();

    const float4* hb4 = reinterpret_cast<const float4*>(hbuf);
    float2* gh2 = reinterpret_cast<float2*>(gh);

    for (int i = 0; i <= T_STEPS; ++i) {
        // Prefetch gi0 row i (layer-0 gate threads); dot phase covers the latency
        float gr = 0.f, gz = 0.f, gn = 0.f;
        if (tid < H_DIM && i < T_STEPS) {
            const float* p = gi0 + (size_t)i * G_DIM + tid;
            gr = p[0]; gz = p[H_DIM]; gn = p[2 * H_DIM];
        }

        // Dot phase: 2 gate pre-activations per thread, packed-f32 FMAs,
        // broadcast ds_read_b128 of the shared h vector.
        f2 acc0, acc1, acc2, acc3;
        acc0.x = bias0; acc0.y = 0.0f;
        acc1.x = 0.0f;  acc1.y = 0.0f;
        acc2.x = bias1; acc2.y = 0.0f;
        acc3.x = 0.0f;  acc3.y = 0.0f;
        #define DOTK(k) { float4 V = hb4[hoff4 + k]; \
                          f2 va, vb; va.x = V.x; va.y = V.y; vb.x = V.z; vb.y = V.w; \
                          acc0 += w0a_##k * va; acc1 += w0b_##k * vb; \
                          acc2 += w1a_##k * va; acc3 += w1b_##k * vb; }
        REP25(DOTK)
        #undef DOTK
        if (active) {
            float a = (acc0.x + acc1.x) + (acc0.y + acc1.y);
            float b = (acc2.x + acc3.x) + (acc2.y + acc3.y);
            gh2[ghw] = make_float2(a, b);
        }
        __syncthreads();

        // Gate phase
        if (tid < H_DIM) {
            if (i < T_STEPS) {   // h1[i]
                float r = 1.0f / (1.0f + expf(-(gr + gh[tid])));
                float z = 1.0f / (1.0f + expf(-(gz + gh[H_DIM + tid])));
                float n = tanhf(gn + r * gh[2 * H_DIM + tid]);
                float hp = hbuf[tid];
                hbuf[tid] = (1.0f - z) * n + z * hp;
            }
        } else if (tid >= 256 && tid < 256 + H_DIM) {
            if (i >= 1) {        // h2[i-1]
                int j = tid - 256;
                float r = 1.0f / (1.0f + expf(-(gh[G_DIM + j] + gh[2 * G_DIM + j])));
                float z = 1.0f / (1.0f + expf(-(gh[G_DIM + H_DIM + j] + gh[2 * G_DIM + H_DIM + j])));
                float n = tanhf(gh[G_DIM + 2 * H_DIM + j] + r * gh[2 * G_DIM + 2 * H_DIM + j]);
                float hp = hbuf[128 + j];
                hbuf[128 + j] = (1.0f - z) * n + z * hp;
            }
        }
        __syncthreads();
    }

    // FC epilogue: out = fc_b + fc_w . h2[T-1]
    if (tid < 64) {
        float s = 0.0f;
        for (int j = tid; j < H_DIM; j += 64) s = fmaf(fc_w[j], hbuf[128 + j], s);
        #pragma unroll
        for (int off = 32; off > 0; off >>= 1) s += __shfl_down(s, off);
        if (tid == 0) out[0] = s + fc_b[0];
    }
}

extern "C" void kernel_launch(void* const* d_in, const int* in_sizes, int n_in,
                              void* d_out, int out_size, void* d_ws, size_t ws_size,
                              hipStream_t stream) {
    const float* x     = (const float*)d_in[0];
    const float* w_ih0 = (const float*)d_in[1];
    const float* w_hh0 = (const float*)d_in[2];
    const float* b_ih0 = (const float*)d_in[3];
    const float* b_hh0 = (const float*)d_in[4];
    const float* w_ih1 = (const float*)d_in[5];
    const float* w_hh1 = (const float*)d_in[6];
    const float* b_ih1 = (const float*)d_in[7];
    const float* b_hh1 = (const float*)d_in[8];
    const float* fc_w  = (const float*)d_in[9];
    const float* fc_b  = (const float*)d_in[10];
    float* out = (float*)d_out;
    float* gi0 = (float*)d_ws;   // T*300 floats = 19.66 MB

    const int total = T_STEPS * G_DIM;
    gi0_kernel<<<(total + 255) / 256, 256, 0, stream>>>(x, w_ih0, b_ih0, gi0);
    gru_seq_kernel<<<1, 512, 0, stream>>>(gi0, w_hh0, b_hh0, w_ih1, b_ih1,
                                          w_hh1, b_hh1, fc_w, fc_b, out);
}